// Round 7
// baseline (372.839 us; speedup 1.0000x reference)
//
#include <hip/hip_runtime.h>
#include <math.h>

#define BATCH  16
#define F_IN   16
#define F_OUT  64
#define NGRID  32
#define NSPEC  256
#define NU     136           // triangular (l,m>=0) count
#define NITEMS 496           // (m>=0, n) items
#define NP4    3680          // padded (item,l) count: runs padded to multiple of 4
#define SCALING 0.005524271728019903f
#define PI_F 3.14159265358979323846f
#define W32 0.19634954084936207f   // 2*pi/32

// cof2[l] = c_off[l] + 2l(l+1): wig_so3 offset = cof2[l] + m*(2l+1) + n
__device__ const int d_cof2[16] = {0,5,22,59,124,225,370,567,824,1149,1550,2035,2612,3289,4074,4975};
// PB[lam]: padded base of lam-group; run of item (lam,r) starts at PB[lam] + r*pl(lam), pl = (19-lam)&~3
__device__ const int d_PB[16] = {0,16,96,240,448,652,904,1204,1552,1816,2112,2440,2800,2996,3208,3436};

// decode item t (lam-sorted) -> lam, r, m, n
__device__ __forceinline__ void decode_item(int t, int& lam, int& r, int& m, int& n) {
    lam = (int)sqrtf((float)t * 0.5f);
    while ((2*lam + 1) * (lam + 1) <= t) ++lam;
    while (lam > 0 && (2*lam - 1) * lam > t) --lam;
    r = t - (2*lam - 1) * lam;
    if (r < 2*lam + 1) { m = lam; n = r - lam; }
    else { const int r2 = r - (2*lam + 1); m = r2 >> 1; n = (r2 & 1) ? lam : -lam; }
}

// decode padded index p4 -> l, m, n, valid
__device__ __forceinline__ void decode_p4(int p4, int& l, int& m, int& n, int& valid) {
    int lam = 0;
    #pragma unroll
    for (int q = 1; q < 16; ++q) if (p4 >= d_PB[q]) lam = q;
    const int pl = (19 - lam) & ~3;
    const int q2 = p4 - d_PB[lam];
    int ti = q2 / pl;
    const int j = q2 - ti * pl;
    l = lam + j;
    valid = (j < 16 - lam);
    if (l > 15) l = 15;
    if (ti < 2*lam + 1) { m = lam; n = ti - lam; }
    else { const int r2 = ti - (2*lam + 1); m = r2 >> 1; n = (r2 & 1) ? lam : -lam; }
}

// ---------------- K_prep: k1 (0..255) | k2 (256..511) | wigt4+p4lut (512..626) | itemlut (627..628) ----
__global__ __launch_bounds__(256) void k_prep(const float* __restrict__ x,
                                              const float* __restrict__ wig_s2,
                                              const float* __restrict__ kern,
                                              const float* __restrict__ fk_re,
                                              const float* __restrict__ fk_im,
                                              const float* __restrict__ wig,
                                              float2* __restrict__ fhat,
                                              float2* __restrict__ psic,
                                              float4* __restrict__ wigt4,
                                              unsigned int* __restrict__ p4lut,
                                              unsigned int* __restrict__ itemlut) {
    __shared__ __align__(16) char smem[25088];
    const int blk = blockIdx.x;
    const int tid = threadIdx.x;

    if (blk < 256) {
        // ---- k1: fhat_t[b][u][f] ----
        float (*xs)[65]  = (float (*)[65])smem;            // 64*65*4 = 16640
        float2 (*xf)[65] = (float2 (*)[65])(smem + 16640); // 16*65*8 = 8320
        const int b = blk >> 4, f = blk & 15;

        const float4* src = (const float4*)(x + (size_t)(b * F_IN + f) * 4096);
        for (int t = tid; t < 1024; t += 256) {
            float4 v = src[t];
            const int row = t >> 4, col = (t & 15) * 4;
            xs[row][col] = v.x; xs[row][col+1] = v.y; xs[row][col+2] = v.z; xs[row][col+3] = v.w;
        }
        __syncthreads();
        {
            const int m = tid >> 4, j0 = tid & 15;
            float stc, sts;
            sincosf(-(2.f * PI_F / 64.f) * (float)m, &sts, &stc);
            float wr = 1.f, wi = 0.f;
            float ar[4] = {0,0,0,0}, ai[4] = {0,0,0,0};
            #pragma unroll 8
            for (int a = 0; a < 64; ++a) {
                #pragma unroll
                for (int q = 0; q < 4; ++q) {
                    const float v = xs[j0 + 16*q][a];
                    ar[q] += v * wr; ai[q] += v * wi;
                }
                const float nr = wr*stc - wi*sts; wi = wr*sts + wi*stc; wr = nr;
            }
            #pragma unroll
            for (int q = 0; q < 4; ++q) xf[m][j0 + 16*q] = make_float2(ar[q], ai[q]);
        }
        __syncthreads();
        if (tid < NU) {
            int l = (int)((sqrtf(8.f * (float)tid + 1.f) - 1.f) * 0.5f);
            while ((l + 1) * (l + 2) / 2 <= tid) ++l;
            while (l * (l + 1) / 2 > tid) --l;
            const int m = tid - l * (l + 1) / 2;
            const int s = l * l + l + m;
            float re = 0.f, im = 0.f;
            #pragma unroll 8
            for (int j = 0; j < 64; ++j) {
                const float2 v = xf[m][j];
                const float w = wig_s2[j * NSPEC + s];
                re += v.x * w; im += v.y * w;
            }
            fhat[(b * NU + tid) * F_IN + f] = make_float2(re, im);
        }
    } else if (blk < 512) {
        // ---- k2: psic_t[o][s][i] ----
        float2* fk = (float2*)smem;
        const int s = blk - 256;
        if (tid < NGRID) fk[tid] = make_float2(fk_re[s * NGRID + tid], -fk_im[s * NGRID + tid]);
        __syncthreads();
        for (int t = tid; t < F_OUT * F_IN; t += 256) {
            const int o = t >> 4, i = t & 15;
            const float4* kr = (const float4*)(kern + (size_t)(i * F_OUT + o) * NGRID);
            float re = 0.f, im = 0.f;
            #pragma unroll
            for (int g4 = 0; g4 < 8; ++g4) {
                const float4 v = kr[g4];
                const float2 a = fk[g4*4+0], b2 = fk[g4*4+1], c = fk[g4*4+2], d = fk[g4*4+3];
                re += v.x * a.x + v.y * b2.x + v.z * c.x + v.w * d.x;
                im += v.x * a.y + v.y * b2.y + v.z * c.y + v.w * d.y;
            }
            psic[(o * NSPEC + s) * F_IN + i] = make_float2(re * SCALING, im * SCALING);
        }
    } else if (blk < 627) {
        // ---- wigt4[kc][p4] (+ p4lut when kc==0) ----
        const int t = (blk - 512) * 256 + tid;
        if (t < NP4 * 8) {
            const int p4 = t >> 3, kc = t & 7;
            int l, m, n, valid;
            decode_p4(p4, l, m, n, valid);
            const int wo = d_cof2[l] + m * (2 * l + 1) + n;
            float4 v = make_float4(0.f, 0.f, 0.f, 0.f);
            if (valid) {
                v.x = wig[(kc * 4 + 0) * 5456 + wo];
                v.y = wig[(kc * 4 + 1) * 5456 + wo];
                v.z = wig[(kc * 4 + 2) * 5456 + wo];
                v.w = wig[(kc * 4 + 3) * 5456 + wo];
            }
            wigt4[(size_t)kc * NP4 + p4] = v;
            if (kc == 0) {
                const int u  = l * (l + 1) / 2 + m;
                const int sn = l * l + l + n;
                p4lut[p4] = (unsigned)u | ((unsigned)sn << 8) | ((unsigned)valid << 16);
            }
        }
    } else {
        // ---- itemlut[t]: O4 | m<<12 | nn<<16 | nq<<21 ----
        const int t = (blk - 627) * 256 + tid;
        if (t < NITEMS) {
            int lam, r, m, n;
            decode_item(t, lam, r, m, n);
            const int pl = (19 - lam) & ~3;
            const int O4 = d_PB[lam] + r * pl;
            const int nq = pl >> 2;
            itemlut[t] = (unsigned)O4 | ((unsigned)m << 12) | ((unsigned)(n + 15) << 16) | ((unsigned)nq << 21);
        }
    }
}

// ---------------- K3a: fzp4[bo][p4] (padded, zeros in pad), from LDS-staged panels ----------------
__global__ __launch_bounds__(256) void k3a_fz(const float2* __restrict__ fhat,
                                              const float2* __restrict__ psic,
                                              const unsigned int* __restrict__ p4lut,
                                              float2* __restrict__ fzp) {
    __shared__ __align__(16) float2 fh[NU][18];
    __shared__ __align__(16) float2 ps[NSPEC][18];
    const int bo = blockIdx.x;
    const int b = bo >> 6, o = bo & 63;
    const int tid = threadIdx.x;

    {
        const float2* src = fhat + (size_t)b * NU * F_IN;
        for (int t = tid; t < NU * F_IN; t += 256) fh[t >> 4][t & 15] = src[t];
        const float2* src2 = psic + (size_t)o * NSPEC * F_IN;
        for (int t = tid; t < NSPEC * F_IN; t += 256) ps[t >> 4][t & 15] = src2[t];
    }
    __syncthreads();

    float2* dst = fzp + (size_t)bo * NP4;
    for (int p = tid; p < NP4; p += 256) {
        const unsigned e = p4lut[p];
        float2 outv = make_float2(0.f, 0.f);
        if (e >> 16) {
            const int u = e & 255, sn = (e >> 8) & 255;
            const float4* A4 = (const float4*)&fh[u][0];
            const float4* C4 = (const float4*)&ps[sn][0];
            float re = 0.f, im = 0.f;
            #pragma unroll
            for (int i2 = 0; i2 < 8; ++i2) {
                const float4 A = A4[i2], C = C4[i2];
                re += A.x*C.x - A.y*C.y + A.z*C.z - A.w*C.w;
                im += A.x*C.y + A.y*C.x + A.z*C.w + A.w*C.z;
            }
            outv = make_float2(re, im);
        }
        dst[p] = outv;
    }
}

// ---------------- K3c: per (bo, 4 k's): S (padded unroll-4 stream) -> radix-4 G -> radix-4 out ----
__global__ __launch_bounds__(256) void k3c_main(const float2* __restrict__ fzp,
                                               const float4* __restrict__ wigt4,
                                               const unsigned int* __restrict__ itemlut,
                                               const float* __restrict__ bias,
                                               float* __restrict__ out) {
    __shared__ __align__(16) float2 S[4][16][33];   // 16896 B
    __shared__ __align__(16) float2 G[4][16][33];   // 16896 B
    __shared__ float2 tw[32];                       // e^{+i q w}
    const int bo = blockIdx.x >> 3;
    const int kc = blockIdx.x & 7;
    const int tid = threadIdx.x;
    const float bb = bias[bo & 63];

    if (tid < 32) {
        float s_, c_;
        sincosf(W32 * (float)tid, &s_, &c_);
        tw[tid] = make_float2(c_, s_);
    }

    const float2* fzb = fzp + (size_t)bo * NP4;
    const float4* wtb = wigt4 + (size_t)kc * NP4;

    // ----- S-stage: 496 items; padded runs, unroll-4 inner -----
    #pragma unroll
    for (int it = 0; it < 2; ++it) {
        const int t = tid + it * 256;
        if (t < NITEMS) {
            const unsigned e = itemlut[t];
            const int O4 = e & 0xFFF, m = (e >> 12) & 15, nn = (e >> 16) & 31, nq = (e >> 21) & 7;
            const float2* fz = fzb + O4;
            const float4* wt = wtb + O4;
            float sr0=0,si0=0,sr1=0,si1=0,sr2=0,si2=0,sr3=0,si3=0;
            for (int c = 0; c < nq; ++c) {
                #pragma unroll
                for (int j = 0; j < 4; ++j) {
                    const float2 z = fz[j];
                    const float4 w = wt[j];
                    sr0 += z.x * w.x; si0 += z.y * w.x;
                    sr1 += z.x * w.y; si1 += z.y * w.y;
                    sr2 += z.x * w.z; si2 += z.y * w.z;
                    sr3 += z.x * w.w; si3 += z.y * w.w;
                }
                fz += 4; wt += 4;
            }
            S[0][m][nn] = make_float2(sr0, si0);
            S[1][m][nn] = make_float2(sr1, si1);
            S[2][m][nn] = make_float2(sr2, si2);
            S[3][m][nn] = make_float2(sr3, si3);
        }
    }
    __syncthreads();

    // ----- G-phase (radix-4 over n mod 4): class sums C_r(g0), g0 in 0..7; G[g0+8j] = sum_r i^{rj} C_r -----
    {
        const int kk = tid >> 6, m = (tid >> 2) & 15, g0b = tid & 3;
        float cr[2][4], ci[2][4];
        float wr[2], wi[2], str[2], sti[2];
        #pragma unroll
        for (int h = 0; h < 2; ++h) {
            #pragma unroll
            for (int c = 0; c < 4; ++c) { cr[h][c] = 0.f; ci[h][c] = 0.f; }
            const int g = g0b + 4 * h;
            const float2 st = tw[g];                 // e^{i g w}
            const float2 w0 = tw[(-15 * g) & 31];    // e^{-15 i g w}
            str[h] = st.x; sti[h] = st.y;
            wr[h] = w0.x;  wi[h] = w0.y;
        }
        const float2* Srow = &S[kk][m][0];
        #pragma unroll
        for (int nn = 0; nn < 31; ++nn) {
            const float2 sv = Srow[nn];
            const int c = (nn + 1) & 3;              // (n mod 4), n = nn-15
            #pragma unroll
            for (int h = 0; h < 2; ++h) {
                cr[h][c] += sv.x * wr[h] - sv.y * wi[h];
                ci[h][c] += sv.x * wi[h] + sv.y * wr[h];
                const float nwr = wr[h] * str[h] - wi[h] * sti[h];
                wi[h] = wr[h] * sti[h] + wi[h] * str[h];
                wr[h] = nwr;
            }
        }
        #pragma unroll
        for (int h = 0; h < 2; ++h) {
            const int g = g0b + 4 * h;
            G[kk][m][g]      = make_float2(cr[h][0]+cr[h][1]+cr[h][2]+cr[h][3],
                                           ci[h][0]+ci[h][1]+ci[h][2]+ci[h][3]);
            G[kk][m][g + 8]  = make_float2(cr[h][0]-ci[h][1]-cr[h][2]+ci[h][3],
                                           ci[h][0]+cr[h][1]-ci[h][2]-cr[h][3]);
            G[kk][m][g + 16] = make_float2(cr[h][0]-cr[h][1]+cr[h][2]-cr[h][3],
                                           ci[h][0]-ci[h][1]+ci[h][2]-ci[h][3]);
            G[kk][m][g + 24] = make_float2(cr[h][0]+ci[h][1]-cr[h][2]-ci[h][3],
                                           ci[h][0]-cr[h][1]-ci[h][2]+cr[h][3]);
        }
    }
    __syncthreads();

    // ----- out-phase (radix-4 over m mod 4): out[A+8j,g] = base + 2 Re(sum_c i^{cj} D_c(A,g)) -----
    {
        const int kk = tid >> 6, g = tid & 31, a0b = (tid >> 5) & 1;
        const float base = G[kk][0][g].x + bb;
        float* ob = out + (((size_t)bo << 15) + ((size_t)(kc * 4 + kk) << 10));
        #pragma unroll
        for (int pass = 0; pass < 2; ++pass) {
            float d0r[2] = {0,0}, d1r[2] = {0,0}, d1i[2] = {0,0};
            float d2r[2] = {0,0}, d3r[2] = {0,0}, d3i[2] = {0,0};
            float wr[2], wi[2], str[2], sti[2];
            #pragma unroll
            for (int e2 = 0; e2 < 2; ++e2) {
                const int A = a0b + 4 * pass + 2 * e2;
                const float2 st = tw[A];             // e^{i A w}
                str[e2] = st.x; sti[e2] = st.y;
                wr[e2] = st.x;  wi[e2] = st.y;       // w at m=1
            }
            #pragma unroll
            for (int m = 1; m < 16; ++m) {
                const float2 gv = G[kk][m][g];
                const int c = m & 3;
                #pragma unroll
                for (int e2 = 0; e2 < 2; ++e2) {
                    const float X = gv.x * wr[e2] - gv.y * wi[e2];
                    if (c == 0) { d0r[e2] += X; }
                    else if (c == 2) { d2r[e2] += X; }
                    else {
                        const float Y = gv.x * wi[e2] + gv.y * wr[e2];
                        if (c == 1) { d1r[e2] += X; d1i[e2] += Y; }
                        else        { d3r[e2] += X; d3i[e2] += Y; }
                    }
                    if (m < 15) {
                        const float nwr = wr[e2] * str[e2] - wi[e2] * sti[e2];
                        wi[e2] = wr[e2] * sti[e2] + wi[e2] * str[e2];
                        wr[e2] = nwr;
                    }
                }
            }
            #pragma unroll
            for (int e2 = 0; e2 < 2; ++e2) {
                const int A = a0b + 4 * pass + 2 * e2;
                const float v0 = fmaf(2.f, d0r[e2] + d1r[e2] + d2r[e2] + d3r[e2], base);
                const float v1 = fmaf(2.f, d0r[e2] - d1i[e2] - d2r[e2] + d3i[e2], base);
                const float v2 = fmaf(2.f, d0r[e2] - d1r[e2] + d2r[e2] - d3r[e2], base);
                const float v3 = fmaf(2.f, d0r[e2] + d1i[e2] - d2r[e2] - d3i[e2], base);
                ob[((A)      << 5) + g] = v0;
                ob[((A + 8)  << 5) + g] = v1;
                ob[((A + 16) << 5) + g] = v2;
                ob[((A + 24) << 5) + g] = v3;
            }
        }
    }
}

extern "C" void kernel_launch(void* const* d_in, const int* in_sizes, int n_in,
                              void* d_out, int out_size, void* d_ws, size_t ws_size,
                              hipStream_t stream) {
    const float* x       = (const float*)d_in[0];
    const float* kern    = (const float*)d_in[1];
    const float* bias    = (const float*)d_in[2];
    const float* wig_s2  = (const float*)d_in[3];
    const float* fk_re   = (const float*)d_in[4];
    const float* fk_im   = (const float*)d_in[5];
    const float* wig_so3 = (const float*)d_in[6];
    float* out = (float*)d_out;

    // ws layout
    float2*       fhat_t  = (float2*)d_ws;                              // 16*136*16*8 = 278528
    float2*       psic_t  = (float2*)((char*)d_ws + 327680);            // 64*256*16*8 = 2097152
    float4*       wigt4   = (float4*)((char*)d_ws + 2424832);           // 8*3680*16   = 470720
    unsigned int* p4lut   = (unsigned int*)((char*)d_ws + 2895872);     // 3680*4      = 14720
    unsigned int* itemlut = (unsigned int*)((char*)d_ws + 2910592);     // 496*4       = 1984
    float2*       fzp4    = (float2*)((char*)d_ws + 2912768);           // 1024*3680*8 = 30146560

    k_prep<<<629, 256, 0, stream>>>(x, wig_s2, kern, fk_re, fk_im, wig_so3,
                                    fhat_t, psic_t, wigt4, p4lut, itemlut);
    k3a_fz<<<BATCH * F_OUT, 256, 0, stream>>>(fhat_t, psic_t, p4lut, fzp4);
    k3c_main<<<BATCH * F_OUT * 8, 256, 0, stream>>>(fzp4, wigt4, itemlut, bias, out);
}